// Round 1
// baseline (434.483 us; speedup 1.0000x reference)
//
#include <hip/hip_runtime.h>
#include <cstdint>
#include <cstddef>

// VarAttention: B=4, N=96, P=64, C=1024, H=16, hd=64. tokens = 24576.
// Buffers are FP32 (reference dtype). Internal compute: bf16 MFMA, fp32 accum.
#define PPP  64
#define CC   1024

typedef __attribute__((ext_vector_type(8))) short short8;
typedef __attribute__((ext_vector_type(4))) float floatx4;
typedef __attribute__((ext_vector_type(4))) unsigned short ushort4v;

__device__ inline float bf2f(unsigned short u) {
  union { unsigned int i; float f; } v; v.i = ((unsigned int)u) << 16; return v.f;
}
__device__ inline unsigned short f2bf(float f) {
  union { float f; unsigned int i; } v; v.f = f;
  unsigned int x = v.i;
  unsigned int r = (x + 0x7fffu + ((x >> 16) & 1u)) >> 16;  // RNE
  return (unsigned short)r;
}

// global->LDS direct DMA, 16B/lane; LDS dest = wave-uniform base + lane*16.
#define GLD16(gp, lp)                                                          \
  __builtin_amdgcn_global_load_lds(                                            \
      (const __attribute__((address_space(1))) void*)(gp),                     \
      (__attribute__((address_space(3))) void*)(lp), 16, 0, 0)

// ---------------------------------------------------------------------------
// Fused convert + mean-pool: one pass over x (96 MB fp32).
// ---------------------------------------------------------------------------
__global__ __launch_bounds__(256) void conv_mean(
    const float* __restrict__ x, unsigned short* __restrict__ xbf,
    unsigned short* __restrict__ xm) {
  int bn = blockIdx.x;
  int c4 = threadIdx.x * 4;
  const float* xp = x + (size_t)bn * (PPP * CC) + c4;
  unsigned short* xo = xbf + (size_t)bn * (PPP * CC) + c4;
  float4 s = {0.f, 0.f, 0.f, 0.f};
#pragma unroll 8
  for (int p = 0; p < PPP; ++p) {
    float4 v = *(const float4*)&xp[(size_t)p * CC];
    s.x += v.x; s.y += v.y; s.z += v.z; s.w += v.w;
    ushort4v pk;
    pk.x = f2bf(v.x); pk.y = f2bf(v.y); pk.z = f2bf(v.z); pk.w = f2bf(v.w);
    *(ushort4v*)&xo[(size_t)p * CC] = pk;
  }
  ushort4v pm;
  pm.x = f2bf(s.x * (1.0f / PPP)); pm.y = f2bf(s.y * (1.0f / PPP));
  pm.z = f2bf(s.z * (1.0f / PPP)); pm.w = f2bf(s.w * (1.0f / PPP));
  *(ushort4v*)&xm[(size_t)bn * CC + c4] = pm;
}

// ---------------------------------------------------------------------------
// Convert+transpose: dst_bf16[c][r] = src_f32[r][c]. Grid (Cc/32, R/32), 256.
// ---------------------------------------------------------------------------
__global__ __launch_bounds__(256) void transpose_f32_bf16(
    const float* __restrict__ src, unsigned short* __restrict__ dst,
    int R, int Cc, int src_stride) {
  __shared__ unsigned short tile[32][33];
  int tc = blockIdx.x * 32, tr = blockIdx.y * 32;
  int tx = threadIdx.x & 31, ty = threadIdx.x >> 5;  // 32 x 8
  for (int yy = ty; yy < 32; yy += 8)
    tile[yy][tx] = f2bf(src[(size_t)(tr + yy) * src_stride + tc + tx]);
  __syncthreads();
  for (int yy = ty; yy < 32; yy += 8)
    dst[(size_t)(tc + yy) * R + tr + tx] = tile[tx][yy];
}

// ---------------------------------------------------------------------------
// Small-M MFMA GEMM (m97 structure) kept for the qk projection only.
// ---------------------------------------------------------------------------
template <bool F32OUT, bool SWIZ>
__global__ __launch_bounds__(256) void gemm_bt(
    const unsigned short* __restrict__ A, const unsigned short* __restrict__ BT,
    void* __restrict__ Cout, const float* __restrict__ bias,
    int M, int N, int K, int nbx) {
  __shared__ unsigned short As[128 * 32];
  __shared__ unsigned short Bs[128 * 32];

  int bx, by;
  {
    int bid = blockIdx.x;
    if (SWIZ) {
      bx = (bid >> 3) & 7;
      by = (bid & 7) * (gridDim.x >> 6) + (bid >> 6);
    } else {
      bx = bid % nbx;
      by = bid / nbx;
    }
  }
  const int rowBase = by * 128;
  const int colBase = bx * 128;
  const int t = threadIdx.x;
  const int wave = t >> 6, lane = t & 63;
  const int qr = wave >> 1, qc = wave & 1;
  const int m16 = lane & 15, quad = lane >> 4;

  floatx4 acc[4][4];
#pragma unroll
  for (int i = 0; i < 4; ++i)
#pragma unroll
    for (int j = 0; j < 4; ++j) {
      acc[i][j][0] = 0.f; acc[i][j][1] = 0.f; acc[i][j][2] = 0.f; acc[i][j][3] = 0.f;
    }

  for (int k0 = 0; k0 < K; k0 += 32) {
    __syncthreads();
#pragma unroll
    for (int u = 0; u < 2; ++u) {
      int ch = (u * 4 + wave) * 64 + lane;      // 0..511
      int row = ch >> 2, c8 = (ch & 3) << 3;    // 16B chunks of a 32-wide k-row
      GLD16(&A [(size_t)(rowBase + row) * K + k0 + c8], &As[ch * 8]);
      GLD16(&BT[(size_t)(colBase + row) * K + k0 + c8], &Bs[ch * 8]);
    }
    __syncthreads();

    short8 af[4], bfr[4];
#pragma unroll
    for (int i = 0; i < 4; ++i)
      af[i] = *(const short8*)&As[(qr * 64 + i * 16 + m16) * 32 + quad * 8];
#pragma unroll
    for (int j = 0; j < 4; ++j)
      bfr[j] = *(const short8*)&Bs[(qc * 64 + j * 16 + m16) * 32 + quad * 8];
#pragma unroll
    for (int i = 0; i < 4; ++i)
#pragma unroll
      for (int j = 0; j < 4; ++j)
        acc[i][j] = __builtin_amdgcn_mfma_f32_16x16x32_bf16(af[i], bfr[j], acc[i][j], 0, 0, 0);
  }

  float bv[4];
#pragma unroll
  for (int j = 0; j < 4; ++j)
    bv[j] = bias ? bias[colBase + qc * 64 + j * 16 + m16] : 0.f;

#pragma unroll
  for (int i = 0; i < 4; ++i) {
    int row0 = rowBase + qr * 64 + i * 16 + quad * 4;
#pragma unroll
    for (int j = 0; j < 4; ++j) {
      int col = colBase + qc * 64 + j * 16 + m16;
#pragma unroll
      for (int r = 0; r < 4; ++r) {
        float f = acc[i][j][r] + bv[j];
        if (F32OUT)
          ((float*)Cout)[(size_t)(row0 + r) * N + col] = f;
        else
          ((unsigned short*)Cout)[(size_t)(row0 + r) * N + col] = f2bf(f);
      }
    }
  }
}

// ---------------------------------------------------------------------------
// 8-phase pipelined MFMA GEMM for the big (M x 1024 x 1024) GEMMs.
// Tile 256x128, BK=64, 8 waves (4Mx2N), per-wave 64x64 output.
// Triple-buffered LDS (144 KiB), depth-2 GLD16 prefetch, counted vmcnt(6),
// raw s_barrier (no vmcnt(0) drain in the loop), setprio(1) around MFMA.
// LDS chunk swizzle: 16B chunk index ^= (row&7); applied as pre-swizzled
// GLOBAL source (gload_lds writes linearly) + swizzled ds_read (rule 21).
// Requires: M%256==0, N%128==0, K%64==0, grid = (M/256)*(N/128), grid%8==0.
// ---------------------------------------------------------------------------
template <bool F32OUT>
__global__ __launch_bounds__(512, 2) void gemm_bt256(
    const unsigned short* __restrict__ A, const unsigned short* __restrict__ BT,
    void* __restrict__ Cout, const float* __restrict__ bias,
    int M, int N, int K) {
  __shared__ __attribute__((aligned(16))) unsigned short As[3][256 * 64];
  __shared__ __attribute__((aligned(16))) unsigned short Bs[3][128 * 64];

  // XCD band mapping: XCD k owns a contiguous tid band (row-tile bands of
  // full-N) so each A panel is reused by its 8 col-blocks inside one L2.
  const int nbx = N >> 7;
  int tid = (blockIdx.x & 7) * (gridDim.x >> 3) + (blockIdx.x >> 3);
  const int bx = tid % nbx, by = tid / nbx;
  const int rowBase = by * 256;
  const int colBase = bx * 128;

  const int t = threadIdx.x;          // 512
  const int wave = t >> 6, lane = t & 63;
  const int wr = wave >> 1, wc = wave & 1;   // 4 x 2 wave grid
  const int m16 = lane & 15, quad = lane >> 4;
  const int sw7 = lane & 7;                  // read-side swizzle key (= row&7)

  // ---- staging geometry: A tile 256x8 chunks (4/thread), B 128x8 (2/thread)
  const unsigned short* srcA[4];
  const unsigned short* srcB[2];
  int offA[4], offB[2];
#pragma unroll
  for (int u = 0; u < 4; ++u) {
    int c = (u * 8 + wave) * 64 + lane;
    int row = c >> 3, pch = c & 7;
    int l = pch ^ (row & 7);                 // logical chunk placed here
    srcA[u] = A + (size_t)(rowBase + row) * K + l * 8;
    offA[u] = c * 8;
  }
#pragma unroll
  for (int u = 0; u < 2; ++u) {
    int c = (u * 8 + wave) * 64 + lane;
    int row = c >> 3, pch = c & 7;
    int l = pch ^ (row & 7);
    srcB[u] = BT + (size_t)(colBase + row) * K + l * 8;
    offB[u] = c * 8;
  }

  floatx4 acc[4][4];
#pragma unroll
  for (int i = 0; i < 4; ++i)
#pragma unroll
    for (int j = 0; j < 4; ++j) {
      acc[i][j][0] = 0.f; acc[i][j][1] = 0.f; acc[i][j][2] = 0.f; acc[i][j][3] = 0.f;
    }

  const int NT = K >> 6;   // 16 K-tiles of 64

  // ---- prologue: stage tiles 0 and 1 (6 loads each, in order)
#pragma unroll
  for (int u = 0; u < 4; ++u) GLD16(srcA[u], &As[0][offA[u]]);
#pragma unroll
  for (int u = 0; u < 2; ++u) GLD16(srcB[u], &Bs[0][offB[u]]);
#pragma unroll
  for (int u = 0; u < 4; ++u) GLD16(srcA[u] + 64, &As[1][offA[u]]);
#pragma unroll
  for (int u = 0; u < 2; ++u) GLD16(srcB[u] + 64, &Bs[1][offB[u]]);

  // ds_read addressing: frag (row) at physical chunk (kh*4+quad)^sw7.
  // row&7 == m16&7 == sw7 for every fragment row (wr*64, i*16 are 0 mod 8).
#define LDA_F(Ac, i, kh) \
  (*(const short8*)&(Ac)[(wr * 64 + (i) * 16 + m16) * 64 + ((((kh) * 4 + quad) ^ sw7) * 8)])
#define LDB_F(Bc, j, kh) \
  (*(const short8*)&(Bc)[(wc * 64 + (j) * 16 + m16) * 64 + ((((kh) * 4 + quad) ^ sw7) * 8)])

  int cur = 0, nb = 2;
#pragma unroll 1
  for (int kt = 0; kt < NT; ++kt) {
    // Wait for THIS wave's tile-kt loads (oldest 6 of <=12 outstanding),
    // then barrier => all waves' tile-kt loads have landed.
    if (kt == NT - 1)
      asm volatile("s_waitcnt vmcnt(0)" ::: "memory");
    else
      asm volatile("s_waitcnt vmcnt(6)" ::: "memory");
    asm volatile("s_barrier" ::: "memory");

    const unsigned short* Ac = &As[cur][0];
    const unsigned short* Bc = &Bs[cur][0];
    const bool st = (kt + 2) < NT;
    const int koff = (kt + 2) << 6;

#pragma unroll
    for (int p = 0; p < 4; ++p) {
      const int i0 = (p >> 1) * 2, i1 = i0 + 1;
      const int j0 = (p & 1) * 2, j1 = j0 + 1;
      // phase issue cluster: 8 ds_read_b128 + staged prefetch portion
      short8 A00 = LDA_F(Ac, i0, 0), A01 = LDA_F(Ac, i0, 1);
      short8 A10 = LDA_F(Ac, i1, 0), A11 = LDA_F(Ac, i1, 1);
      short8 B00 = LDB_F(Bc, j0, 0), B01 = LDB_F(Bc, j0, 1);
      short8 B10 = LDB_F(Bc, j1, 0), B11 = LDB_F(Bc, j1, 1);
      if (st) {
        if (p == 0) {
          GLD16(srcA[0] + koff, &As[nb][offA[0]]);
          GLD16(srcA[1] + koff, &As[nb][offA[1]]);
        } else if (p == 1) {
          GLD16(srcA[2] + koff, &As[nb][offA[2]]);
          GLD16(srcA[3] + koff, &As[nb][offA[3]]);
        } else if (p == 2) {
          GLD16(srcB[0] + koff, &Bs[nb][offB[0]]);
        } else {
          GLD16(srcB[1] + koff, &Bs[nb][offB[1]]);
        }
      }
      asm volatile("s_barrier" ::: "memory");
      __builtin_amdgcn_sched_barrier(0);
      __builtin_amdgcn_s_setprio(1);
      acc[i0][j0] = __builtin_amdgcn_mfma_f32_16x16x32_bf16(A00, B00, acc[i0][j0], 0, 0, 0);
      acc[i0][j0] = __builtin_amdgcn_mfma_f32_16x16x32_bf16(A01, B01, acc[i0][j0], 0, 0, 0);
      acc[i0][j1] = __builtin_amdgcn_mfma_f32_16x16x32_bf16(A00, B10, acc[i0][j1], 0, 0, 0);
      acc[i0][j1] = __builtin_amdgcn_mfma_f32_16x16x32_bf16(A01, B11, acc[i0][j1], 0, 0, 0);
      acc[i1][j0] = __builtin_amdgcn_mfma_f32_16x16x32_bf16(A10, B00, acc[i1][j0], 0, 0, 0);
      acc[i1][j0] = __builtin_amdgcn_mfma_f32_16x16x32_bf16(A11, B01, acc[i1][j0], 0, 0, 0);
      acc[i1][j1] = __builtin_amdgcn_mfma_f32_16x16x32_bf16(A10, B10, acc[i1][j1], 0, 0, 0);
      acc[i1][j1] = __builtin_amdgcn_mfma_f32_16x16x32_bf16(A11, B11, acc[i1][j1], 0, 0, 0);
      __builtin_amdgcn_s_setprio(0);
      __builtin_amdgcn_sched_barrier(0);
      asm volatile("s_barrier" ::: "memory");
    }
    cur = (cur == 2) ? 0 : cur + 1;
    nb = (nb == 2) ? 0 : nb + 1;
  }
#undef LDA_F
#undef LDB_F

  float bv[4];
#pragma unroll
  for (int j = 0; j < 4; ++j)
    bv[j] = bias ? bias[colBase + wc * 64 + j * 16 + m16] : 0.f;

#pragma unroll
  for (int i = 0; i < 4; ++i) {
    int row0 = rowBase + wr * 64 + i * 16 + quad * 4;
#pragma unroll
    for (int j = 0; j < 4; ++j) {
      int col = colBase + wc * 64 + j * 16 + m16;
#pragma unroll
      for (int r = 0; r < 4; ++r) {
        float f = acc[i][j][r] + bv[j];
        if (F32OUT)
          ((float*)Cout)[(size_t)(row0 + r) * N + col] = f;
        else
          ((unsigned short*)Cout)[(size_t)(row0 + r) * N + col] = f2bf(f);
      }
    }
  }
}

// ---------------------------------------------------------------------------
// Per-(b,h) scores + softmax. qk (384 x 2048) fp32: [0,1024)=q, [1024,2048)=k.
// ---------------------------------------------------------------------------
__global__ __launch_bounds__(128) void softmax_k(
    const float* __restrict__ qk, unsigned short* __restrict__ attn) {
  int bh = blockIdx.x;
  int b = bh >> 4, h = bh & 15;
  __shared__ float ks[96][64];   // 24 KB
  __shared__ float sc[96][96];   // 36 KB, [m][t] layout
  int t = threadIdx.x;
  for (int idx = t; idx < 96 * 64; idx += 128) {
    int n = idx >> 6, d = idx & 63;
    ks[n][d] = qk[(size_t)(b * 96 + n) * 2048 + 1024 + h * 64 + d];
  }
  __syncthreads();
  if (t < 96) {
    float qreg[64];
    const float* qrow = qk + (size_t)(b * 96 + t) * 2048 + h * 64;
#pragma unroll
    for (int d = 0; d < 64; ++d) qreg[d] = qrow[d];

    float mx = -1e30f;
    for (int m = 0; m < 96; ++m) {
      float s0 = 0.f, s1 = 0.f, s2 = 0.f, s3 = 0.f;
#pragma unroll
      for (int d = 0; d < 64; d += 4) {
        s0 += qreg[d + 0] * ks[m][d + 0];
        s1 += qreg[d + 1] * ks[m][d + 1];
        s2 += qreg[d + 2] * ks[m][d + 2];
        s3 += qreg[d + 3] * ks[m][d + 3];
      }
      float s = ((s0 + s1) + (s2 + s3)) * 0.125f;  // hd^-0.5
      sc[m][t] = s;
      mx = fmaxf(mx, s);
    }
    float sum = 0.f;
    for (int m = 0; m < 96; ++m) {
      float e = __expf(sc[m][t] - mx);
      sc[m][t] = e;
      sum += e;
    }
    float inv = 1.0f / sum;
    size_t base = (size_t)(bh * 96 + t) * 96;
    for (int m = 0; m < 96; ++m) attn[base + m] = f2bf(sc[m][t] * inv);
  }
}

// ---------------------------------------------------------------------------
// MFMA attn-apply (no LDS). Per (b,h): out2'(96 x 4096) = attn_bh(96x96) @
// V'_bh(96x4096), where V'[m][p*64+d] = V[((b*96+m)*64+p)*1024 + h*64+d].
// ---------------------------------------------------------------------------
__global__ __launch_bounds__(256) void attn_apply_mfma(
    const unsigned short* __restrict__ attn, const unsigned short* __restrict__ V,
    unsigned short* __restrict__ out2) {
  const int bid = blockIdx.x;
  const int bh = bid >> 5, ct = bid & 31;
  const int b = bh >> 4;           // 0 when launched per-batch with grid 512
  const int t = threadIdx.x;
  const int wave = t >> 6, lane = t & 63;
  const int m16 = lane & 15, quad = lane >> 4;

  const unsigned short* An = attn + (size_t)bh * 96 * 96;   // attn[bh][n][m]
  const int vb = b * 96 * 64 * CC;                           // batch offset in V

  floatx4 acc[6][2];
#pragma unroll
  for (int i = 0; i < 6; ++i)
#pragma unroll
    for (int j = 0; j < 2; ++j) {
      acc[i][j][0] = 0.f; acc[i][j][1] = 0.f; acc[i][j][2] = 0.f; acc[i][j][3] = 0.f;
    }

  int p_[2], base_[2];
#pragma unroll
  for (int jj = 0; jj < 2; ++jj) {
    int colL = wave * 32 + jj * 16;              // 0..112, multiple of 16
    int p = ct * 2 + (colL >> 6);
    int d = (colL & 63) + m16;
    p_[jj] = p;
    base_[jj] = vb + p * CC + ((bh & 15) * 64) + d;   // + m*64*CC per k
  }

#pragma unroll
  for (int k0 = 0; k0 < 96; k0 += 32) {
    short8 af[6];
#pragma unroll
    for (int i = 0; i < 6; ++i)
      af[i] = *(const short8*)&An[(i * 16 + m16) * 96 + k0 + quad * 8];
#pragma unroll
    for (int jj = 0; jj < 2; ++jj) {
      short8 bfr;
#pragma unroll
      for (int j = 0; j < 8; ++j)
        bfr[j] = (short)V[(size_t)base_[jj] + (size_t)(k0 + quad * 8 + j) * (64 * CC)];
#pragma unroll
      for (int i = 0; i < 6; ++i)
        acc[i][jj] = __builtin_amdgcn_mfma_f32_16x16x32_bf16(af[i], bfr, acc[i][jj], 0, 0, 0);
    }
  }

#pragma unroll
  for (int jj = 0; jj < 2; ++jj) {
    int colL = wave * 32 + jj * 16;
    int d = (colL & 63) + m16;
    size_t obase = (size_t)(b * 96) * 64 * CC + (size_t)p_[jj] * CC + (bh & 15) * 64 + d;
#pragma unroll
    for (int i = 0; i < 6; ++i) {
#pragma unroll
      for (int r = 0; r < 4; ++r) {
        int n = i * 16 + quad * 4 + r;
        out2[obase + (size_t)n * (64 * CC)] = f2bf(acc[i][jj][r]);
      }
    }
  }
}

// ---------------------------------------------------------------------------
// Buffer plan identical to previous round (see chunked-ordering proof there).
// ---------------------------------------------------------------------------
extern "C" void kernel_launch(void* const* d_in, const int* in_sizes, int n_in,
                              void* d_out, int out_size, void* d_ws, size_t ws_size,
                              hipStream_t stream) {
  const float* x      = (const float*)d_in[0];  // (4,96,64,1024) fp32
  const float* W_qkv  = (const float*)d_in[1];  // (1024,3072) fp32
  const float* W_proj = (const float*)d_in[2];  // (1024,1024) fp32
  const float* b_proj = (const float*)d_in[3];  // (1024,) fp32
  float* out = (float*)d_out;                   // (4,96,64,1024) fp32

  char* w = (char*)d_ws;
  unsigned short* WqkvT = (unsigned short*)(w);                    // 6 MB
  unsigned short* WpT   = (unsigned short*)(w + 6291456);          // 2 MB
  unsigned short* xm    = (unsigned short*)(w + 8388608);          // 0.75 MB
  float*          qkbuf = (float*)(w + 9175040);                   // 3 MB
  unsigned short* attn  = (unsigned short*)(w + 12320768);         // 1.125 MB
  unsigned short* out2w = (unsigned short*)(w + 13500416);         // 48 or 12 MB
  unsigned short* xbf   = (unsigned short*)d_out;                      // 48 MB
  unsigned short* Vbuf  = (unsigned short*)((char*)d_out + 50331648);  // 48 MB

  const bool fullws = ws_size >= (size_t)13500416 + 50331648;

  // 1) fused convert(x->bf16) + mean-pool over P (q/k only need the mean)
  conv_mean<<<dim3(384), 256, 0, stream>>>(x, xbf, xm);

  // 2) weight convert+transpose (B^T bf16 layout)
  transpose_f32_bf16<<<dim3(96, 32), 256, 0, stream>>>(W_qkv, WqkvT, 1024, 3072, 3072);
  transpose_f32_bf16<<<dim3(32, 32), 256, 0, stream>>>(W_proj, WpT, 1024, 1024, 1024);

  // 3) qk = xm @ W_qkv[:, :2048] -> fp32 (small; plain mapping)
  gemm_bt<true, false><<<dim3(48), 256, 0, stream>>>(
      xm, WqkvT, qkbuf, nullptr, 384, 2048, 1024, 16);

  // 4) scores + softmax -> attn bf16
  softmax_k<<<dim3(64), 128, 0, stream>>>(qkbuf, attn);

  // 5) V = xbf @ W_qkv[:, 2048:3072] -> bf16 (8-phase 256x128 pipeline)
  gemm_bt256<false><<<dim3(768), 512, 0, stream>>>(
      xbf, WqkvT + (size_t)2048 * 1024, Vbuf, nullptr, 24576, 1024, 1024);

  if (fullws) {
    // 6) attn-mix, all batches in one launch (64 bh x 32 col-tiles)
    attn_apply_mfma<<<dim3(2048), 256, 0, stream>>>(attn, Vbuf, out2w);
    // 7) out = out2 @ W_proj + b_proj -> fp32, one full-M launch
    gemm_bt256<true><<<dim3(768), 512, 0, stream>>>(
        out2w, WpT, out, b_proj, 24576, 1024, 1024);
  } else {
    for (int b = 0; b < 4; ++b) {
      attn_apply_mfma<<<dim3(512), 256, 0, stream>>>(
          attn + (size_t)b * 16 * 96 * 96,
          Vbuf + (size_t)b * 6144 * 1024,
          out2w);
      gemm_bt256<true><<<dim3(192), 512, 0, stream>>>(
          out2w, WpT, out + (size_t)b * 6144 * 1024, b_proj, 6144, 1024, 1024);
    }
  }
}

// Round 2
// 386.496 us; speedup vs baseline: 1.1242x; 1.1242x over previous
//
#include <hip/hip_runtime.h>
#include <cstdint>
#include <cstddef>

// VarAttention: B=4, N=96, P=64, C=1024, H=16, hd=64. tokens = 24576.
// Buffers are FP32 (reference dtype). Internal compute: bf16 MFMA, fp32 accum.
#define PPP  64
#define CC   1024

typedef __attribute__((ext_vector_type(8))) short short8;
typedef __attribute__((ext_vector_type(4))) float floatx4;
typedef __attribute__((ext_vector_type(4))) unsigned short ushort4v;

__device__ inline float bf2f(unsigned short u) {
  union { unsigned int i; float f; } v; v.i = ((unsigned int)u) << 16; return v.f;
}
__device__ inline unsigned short f2bf(float f) {
  union { float f; unsigned int i; } v; v.f = f;
  unsigned int x = v.i;
  unsigned int r = (x + 0x7fffu + ((x >> 16) & 1u)) >> 16;  // RNE
  return (unsigned short)r;
}

// global->LDS direct DMA, 16B/lane; LDS dest = wave-uniform base + lane*16.
#define GLD16(gp, lp)                                                          \
  __builtin_amdgcn_global_load_lds(                                            \
      (const __attribute__((address_space(1))) void*)(gp),                     \
      (__attribute__((address_space(3))) void*)(lp), 16, 0, 0)

// ---------------------------------------------------------------------------
// Fused convert + mean-pool: one pass over x (96 MB fp32).
// ---------------------------------------------------------------------------
__global__ __launch_bounds__(256) void conv_mean(
    const float* __restrict__ x, unsigned short* __restrict__ xbf,
    unsigned short* __restrict__ xm) {
  int bn = blockIdx.x;
  int c4 = threadIdx.x * 4;
  const float* xp = x + (size_t)bn * (PPP * CC) + c4;
  unsigned short* xo = xbf + (size_t)bn * (PPP * CC) + c4;
  float4 s = {0.f, 0.f, 0.f, 0.f};
#pragma unroll 8
  for (int p = 0; p < PPP; ++p) {
    float4 v = *(const float4*)&xp[(size_t)p * CC];
    s.x += v.x; s.y += v.y; s.z += v.z; s.w += v.w;
    ushort4v pk;
    pk.x = f2bf(v.x); pk.y = f2bf(v.y); pk.z = f2bf(v.z); pk.w = f2bf(v.w);
    *(ushort4v*)&xo[(size_t)p * CC] = pk;
  }
  ushort4v pm;
  pm.x = f2bf(s.x * (1.0f / PPP)); pm.y = f2bf(s.y * (1.0f / PPP));
  pm.z = f2bf(s.z * (1.0f / PPP)); pm.w = f2bf(s.w * (1.0f / PPP));
  *(ushort4v*)&xm[(size_t)bn * CC + c4] = pm;
}

// ---------------------------------------------------------------------------
// Convert+transpose: dst_bf16[c][r] = src_f32[r][c]. Grid (Cc/32, R/32), 256.
// ---------------------------------------------------------------------------
__global__ __launch_bounds__(256) void transpose_f32_bf16(
    const float* __restrict__ src, unsigned short* __restrict__ dst,
    int R, int Cc, int src_stride) {
  __shared__ unsigned short tile[32][33];
  int tc = blockIdx.x * 32, tr = blockIdx.y * 32;
  int tx = threadIdx.x & 31, ty = threadIdx.x >> 5;  // 32 x 8
  for (int yy = ty; yy < 32; yy += 8)
    tile[yy][tx] = f2bf(src[(size_t)(tr + yy) * src_stride + tc + tx]);
  __syncthreads();
  for (int yy = ty; yy < 32; yy += 8)
    dst[(size_t)(tc + yy) * R + tr + tx] = tile[tx][yy];
}

// ---------------------------------------------------------------------------
// Small-M MFMA GEMM (m97 structure) kept for the qk projection only.
// ---------------------------------------------------------------------------
template <bool F32OUT, bool SWIZ>
__global__ __launch_bounds__(256) void gemm_bt(
    const unsigned short* __restrict__ A, const unsigned short* __restrict__ BT,
    void* __restrict__ Cout, const float* __restrict__ bias,
    int M, int N, int K, int nbx) {
  __shared__ unsigned short As[128 * 32];
  __shared__ unsigned short Bs[128 * 32];

  int bx, by;
  {
    int bid = blockIdx.x;
    if (SWIZ) {
      bx = (bid >> 3) & 7;
      by = (bid & 7) * (gridDim.x >> 6) + (bid >> 6);
    } else {
      bx = bid % nbx;
      by = bid / nbx;
    }
  }
  const int rowBase = by * 128;
  const int colBase = bx * 128;
  const int t = threadIdx.x;
  const int wave = t >> 6, lane = t & 63;
  const int qr = wave >> 1, qc = wave & 1;
  const int m16 = lane & 15, quad = lane >> 4;

  floatx4 acc[4][4];
#pragma unroll
  for (int i = 0; i < 4; ++i)
#pragma unroll
    for (int j = 0; j < 4; ++j) {
      acc[i][j][0] = 0.f; acc[i][j][1] = 0.f; acc[i][j][2] = 0.f; acc[i][j][3] = 0.f;
    }

  for (int k0 = 0; k0 < K; k0 += 32) {
    __syncthreads();
#pragma unroll
    for (int u = 0; u < 2; ++u) {
      int ch = (u * 4 + wave) * 64 + lane;      // 0..511
      int row = ch >> 2, c8 = (ch & 3) << 3;    // 16B chunks of a 32-wide k-row
      GLD16(&A [(size_t)(rowBase + row) * K + k0 + c8], &As[ch * 8]);
      GLD16(&BT[(size_t)(colBase + row) * K + k0 + c8], &Bs[ch * 8]);
    }
    __syncthreads();

    short8 af[4], bfr[4];
#pragma unroll
    for (int i = 0; i < 4; ++i)
      af[i] = *(const short8*)&As[(qr * 64 + i * 16 + m16) * 32 + quad * 8];
#pragma unroll
    for (int j = 0; j < 4; ++j)
      bfr[j] = *(const short8*)&Bs[(qc * 64 + j * 16 + m16) * 32 + quad * 8];
#pragma unroll
    for (int i = 0; i < 4; ++i)
#pragma unroll
      for (int j = 0; j < 4; ++j)
        acc[i][j] = __builtin_amdgcn_mfma_f32_16x16x32_bf16(af[i], bfr[j], acc[i][j], 0, 0, 0);
  }

  float bv[4];
#pragma unroll
  for (int j = 0; j < 4; ++j)
    bv[j] = bias ? bias[colBase + qc * 64 + j * 16 + m16] : 0.f;

#pragma unroll
  for (int i = 0; i < 4; ++i) {
    int row0 = rowBase + qr * 64 + i * 16 + quad * 4;
#pragma unroll
    for (int j = 0; j < 4; ++j) {
      int col = colBase + qc * 64 + j * 16 + m16;
#pragma unroll
      for (int r = 0; r < 4; ++r) {
        float f = acc[i][j][r] + bv[j];
        if (F32OUT)
          ((float*)Cout)[(size_t)(row0 + r) * N + col] = f;
        else
          ((unsigned short*)Cout)[(size_t)(row0 + r) * N + col] = f2bf(f);
      }
    }
  }
}

// ---------------------------------------------------------------------------
// Pipelined MFMA GEMM for the big (M x 1024 x 1024) GEMMs.
// Tile 256x256, BK=64, 8 waves (2M x 4N), per-wave 128x64 output, every
// fragment read from LDS EXACTLY ONCE per K-tile (24 ds_read_b128 -> 64 MFMA
// per wave per K-tile; ratio 2.67).
// Double-buffered LDS (128 KiB). Loads split into 4 consumption-ordered
// stage groups (2 GLD16/thread/phase); counted s_waitcnt vmcnt(4) at phase
// heads (never drains in the loop), ONE s_barrier per phase (leading edge
// only -- dbuf: stages write buf^1, reads from buf; the P0 barrier of tile
// kt proves all waves retired tile kt-1's reads before any overwrite).
// Issue->consume distance = 3-4 phases (~HBM latency). Last tile peeled
// with waits 4/2/0. setprio(1) around each 16-MFMA cluster.
// Swizzle: 16B-chunk index ^= (row&7); linear LDS dest + pre-swizzled
// global source + swizzled ds_read (rule 21). Conflict-free per quarter-wave.
// Requires: M%256==0, N%256==0, K%64==0, K>=128, grid%8==0.
// ---------------------------------------------------------------------------
template <bool F32OUT>
__global__ __launch_bounds__(512, 2) void gemm_bt256(
    const unsigned short* __restrict__ A, const unsigned short* __restrict__ BT,
    void* __restrict__ Cout, const float* __restrict__ bias,
    int M, int N, int K) {
  __shared__ __attribute__((aligned(16))) unsigned short As[2][256 * 64];
  __shared__ __attribute__((aligned(16))) unsigned short Bs[2][256 * 64];

  const int nbx = N >> 8;
  int tid = (blockIdx.x & 7) * (gridDim.x >> 3) + (blockIdx.x >> 3);
  const int bx = tid % nbx, by = tid / nbx;
  const int rowBase = by * 256, colBase = bx * 256;

  const int t = threadIdx.x;          // 512
  const int wave = t >> 6, lane = t & 63;
  const int wr = wave >> 2, wc = wave & 3;   // 2M x 4N wave grid
  const int m16 = lane & 15, quad = lane >> 4;
  const int sw7 = m16 & 7;                   // read-side swizzle key (= row&7)

  // A stage groups u=0..3 = rows u*64..u*64+63, 1 load/thread each.
  const unsigned short* srcA[4];
  int offA[4];
#pragma unroll
  for (int u = 0; u < 4; ++u) {
    int c = u * 512 + t;                     // chunk = row*8 + physchunk
    int row = c >> 3, pch = c & 7;
    int l = pch ^ (row & 7);                 // logical chunk placed here
    srcA[u] = A + (size_t)(rowBase + row) * K + l * 8;
    offA[u] = c * 8;                         // shorts
  }
  // B stage groups g=0,1 = cols with (col>>5)&1==g (32-col interleave,
  // matching per-phase consumption cols wc*64+qb*32..+31), 2 loads each.
  const unsigned short* srcB[2][2];
  int offB[2][2];
#pragma unroll
  for (int g = 0; g < 2; ++g)
#pragma unroll
    for (int u = 0; u < 2; ++u) {
      int i = u * 512 + t;
      int col = g * 32 + ((i >> 8) << 6) + ((i >> 3) & 31);
      int kcp = i & 7;
      int l = kcp ^ (col & 7);
      srcB[g][u] = BT + (size_t)(colBase + col) * K + l * 8;
      offB[g][u] = col * 64 + kcp * 8;       // shorts
    }

  floatx4 acc[8][4];
#pragma unroll
  for (int i = 0; i < 8; ++i)
#pragma unroll
    for (int j = 0; j < 4; ++j) {
      acc[i][j][0] = 0.f; acc[i][j][1] = 0.f; acc[i][j][2] = 0.f; acc[i][j][3] = 0.f;
    }

  short8 ar[4][2];        // A frags of current qa: [i][kh]
  short8 br[2][2][2];     // B frags, both halves live: [qb][j][kh]

#define RD_A(buf, qa)                                                          \
  _Pragma("unroll") for (int i_ = 0; i_ < 4; ++i_)                             \
  _Pragma("unroll") for (int kh_ = 0; kh_ < 2; ++kh_)                          \
    ar[i_][kh_] = *(const short8*)&As[buf][                                    \
        (wr * 128 + (qa) * 64 + i_ * 16 + m16) * 64 +                          \
        (((kh_ * 4 + quad) ^ sw7) * 8)];
#define RD_B(buf, qb)                                                          \
  _Pragma("unroll") for (int j_ = 0; j_ < 2; ++j_)                             \
  _Pragma("unroll") for (int kh_ = 0; kh_ < 2; ++kh_)                          \
    br[qb][j_][kh_] = *(const short8*)&Bs[buf][                                \
        (wc * 64 + (qb) * 32 + j_ * 16 + m16) * 64 +                           \
        (((kh_ * 4 + quad) ^ sw7) * 8)];
#define MFMA_PH(qa, qb)                                                        \
  __builtin_amdgcn_sched_barrier(0);                                           \
  __builtin_amdgcn_s_setprio(1);                                               \
  _Pragma("unroll") for (int kh_ = 0; kh_ < 2; ++kh_)                          \
  _Pragma("unroll") for (int i_ = 0; i_ < 4; ++i_)                             \
  _Pragma("unroll") for (int j_ = 0; j_ < 2; ++j_)                             \
    acc[(qa) * 4 + i_][(qb) * 2 + j_] =                                        \
        __builtin_amdgcn_mfma_f32_16x16x32_bf16(                               \
            ar[i_][kh_], br[qb][j_][kh_], acc[(qa) * 4 + i_][(qb) * 2 + j_],   \
            0, 0, 0);                                                          \
  __builtin_amdgcn_s_setprio(0);                                               \
  __builtin_amdgcn_sched_barrier(0);
#define WAITV(n) asm volatile("s_waitcnt vmcnt(" #n ")" ::: "memory")
#define BAR() asm volatile("s_barrier" ::: "memory")

  // Prologue: stage tile 0 in canonical order (Ag0,Ag2 | Bg0 | Bg1 | Ag1,Ag3)
  GLD16(srcA[0], &As[0][offA[0]]);
  GLD16(srcA[2], &As[0][offA[2]]);
  GLD16(srcB[0][0], &Bs[0][offB[0][0]]);
  GLD16(srcB[0][1], &Bs[0][offB[0][1]]);
  GLD16(srcB[1][0], &Bs[0][offB[1][0]]);
  GLD16(srcB[1][1], &Bs[0][offB[1][1]]);
  GLD16(srcA[1], &As[0][offA[1]]);
  GLD16(srcA[3], &As[0][offA[3]]);

  const int NT = K >> 6;
  int cur = 0;
#pragma unroll 1
  for (int kt = 0; kt < NT - 1; ++kt, cur ^= 1) {
    const int nxt = cur ^ 1;
    const int ko = (kt + 1) << 6;            // shorts offset into K
    // ---- P0: needs Ag0,Ag2,Bg0 of tile kt (oldest 4 of 8 outstanding)
    WAITV(4); BAR();
    RD_A(cur, 0); RD_B(cur, 0);              // 12 ds_read_b128
    GLD16(srcA[0] + ko, &As[nxt][offA[0]]);
    GLD16(srcA[2] + ko, &As[nxt][offA[2]]);
    MFMA_PH(0, 0);
    // ---- P1: needs Bg1 of tile kt
    WAITV(4); BAR();
    RD_B(cur, 1);                            // 4 reads
    GLD16(srcB[0][0] + ko, &Bs[nxt][offB[0][0]]);
    GLD16(srcB[0][1] + ko, &Bs[nxt][offB[0][1]]);
    MFMA_PH(0, 1);
    // ---- P2: needs Ag1,Ag3 of tile kt
    WAITV(4); BAR();
    RD_A(cur, 1);                            // 8 reads
    GLD16(srcB[1][0] + ko, &Bs[nxt][offB[1][0]]);
    GLD16(srcB[1][1] + ko, &Bs[nxt][offB[1][1]]);
    MFMA_PH(1, 0);
    // ---- P3: all frags already in registers
    GLD16(srcA[1] + ko, &As[nxt][offA[1]]);
    GLD16(srcA[3] + ko, &As[nxt][offA[3]]);
    MFMA_PH(1, 1);
  }
  // ---- peeled last tile (no staging; waits drain 4 -> 2 -> 0)
  WAITV(4); BAR();
  RD_A(cur, 0); RD_B(cur, 0);
  MFMA_PH(0, 0);
  WAITV(2); BAR();
  RD_B(cur, 1);
  MFMA_PH(0, 1);
  WAITV(0); BAR();
  RD_A(cur, 1);
  MFMA_PH(1, 0);
  MFMA_PH(1, 1);

#undef RD_A
#undef RD_B
#undef MFMA_PH
#undef WAITV
#undef BAR

  float bv[4];
#pragma unroll
  for (int jg = 0; jg < 4; ++jg)
    bv[jg] = bias ? bias[colBase + wc * 64 + jg * 16 + m16] : 0.f;

#pragma unroll
  for (int ig = 0; ig < 8; ++ig) {
    int row0 = rowBase + wr * 128 + ig * 16 + quad * 4;
#pragma unroll
    for (int jg = 0; jg < 4; ++jg) {
      int col = colBase + wc * 64 + jg * 16 + m16;
#pragma unroll
      for (int r = 0; r < 4; ++r) {
        float f = acc[ig][jg][r] + bv[jg];
        if (F32OUT)
          ((float*)Cout)[(size_t)(row0 + r) * N + col] = f;
        else
          ((unsigned short*)Cout)[(size_t)(row0 + r) * N + col] = f2bf(f);
      }
    }
  }
}

// ---------------------------------------------------------------------------
// Per-(b,h) scores + softmax. qk (384 x 2048) fp32: [0,1024)=q, [1024,2048)=k.
// ---------------------------------------------------------------------------
__global__ __launch_bounds__(128) void softmax_k(
    const float* __restrict__ qk, unsigned short* __restrict__ attn) {
  int bh = blockIdx.x;
  int b = bh >> 4, h = bh & 15;
  __shared__ float ks[96][64];   // 24 KB
  __shared__ float sc[96][96];   // 36 KB, [m][t] layout
  int t = threadIdx.x;
  for (int idx = t; idx < 96 * 64; idx += 128) {
    int n = idx >> 6, d = idx & 63;
    ks[n][d] = qk[(size_t)(b * 96 + n) * 2048 + 1024 + h * 64 + d];
  }
  __syncthreads();
  if (t < 96) {
    float qreg[64];
    const float* qrow = qk + (size_t)(b * 96 + t) * 2048 + h * 64;
#pragma unroll
    for (int d = 0; d < 64; ++d) qreg[d] = qrow[d];

    float mx = -1e30f;
    for (int m = 0; m < 96; ++m) {
      float s0 = 0.f, s1 = 0.f, s2 = 0.f, s3 = 0.f;
#pragma unroll
      for (int d = 0; d < 64; d += 4) {
        s0 += qreg[d + 0] * ks[m][d + 0];
        s1 += qreg[d + 1] * ks[m][d + 1];
        s2 += qreg[d + 2] * ks[m][d + 2];
        s3 += qreg[d + 3] * ks[m][d + 3];
      }
      float s = ((s0 + s1) + (s2 + s3)) * 0.125f;  // hd^-0.5
      sc[m][t] = s;
      mx = fmaxf(mx, s);
    }
    float sum = 0.f;
    for (int m = 0; m < 96; ++m) {
      float e = __expf(sc[m][t] - mx);
      sc[m][t] = e;
      sum += e;
    }
    float inv = 1.0f / sum;
    size_t base = (size_t)(bh * 96 + t) * 96;
    for (int m = 0; m < 96; ++m) attn[base + m] = f2bf(sc[m][t] * inv);
  }
}

// ---------------------------------------------------------------------------
// MFMA attn-apply (no LDS). Per (b,h): out2'(96 x 4096) = attn_bh(96x96) @
// V'_bh(96x4096), where V'[m][p*64+d] = V[((b*96+m)*64+p)*1024 + h*64+d].
// ---------------------------------------------------------------------------
__global__ __launch_bounds__(256) void attn_apply_mfma(
    const unsigned short* __restrict__ attn, const unsigned short* __restrict__ V,
    unsigned short* __restrict__ out2) {
  const int bid = blockIdx.x;
  const int bh = bid >> 5, ct = bid & 31;
  const int b = bh >> 4;           // 0 when launched per-batch with grid 512
  const int t = threadIdx.x;
  const int wave = t >> 6, lane = t & 63;
  const int m16 = lane & 15, quad = lane >> 4;

  const unsigned short* An = attn + (size_t)bh * 96 * 96;   // attn[bh][n][m]
  const int vb = b * 96 * 64 * CC;                           // batch offset in V

  floatx4 acc[6][2];
#pragma unroll
  for (int i = 0; i < 6; ++i)
#pragma unroll
    for (int j = 0; j < 2; ++j) {
      acc[i][j][0] = 0.f; acc[i][j][1] = 0.f; acc[i][j][2] = 0.f; acc[i][j][3] = 0.f;
    }

  int p_[2], base_[2];
#pragma unroll
  for (int jj = 0; jj < 2; ++jj) {
    int colL = wave * 32 + jj * 16;              // 0..112, multiple of 16
    int p = ct * 2 + (colL >> 6);
    int d = (colL & 63) + m16;
    p_[jj] = p;
    base_[jj] = vb + p * CC + ((bh & 15) * 64) + d;   // + m*64*CC per k
  }

#pragma unroll
  for (int k0 = 0; k0 < 96; k0 += 32) {
    short8 af[6];
#pragma unroll
    for (int i = 0; i < 6; ++i)
      af[i] = *(const short8*)&An[(i * 16 + m16) * 96 + k0 + quad * 8];
#pragma unroll
    for (int jj = 0; jj < 2; ++jj) {
      short8 bfr;
#pragma unroll
      for (int j = 0; j < 8; ++j)
        bfr[j] = (short)V[(size_t)base_[jj] + (size_t)(k0 + quad * 8 + j) * (64 * CC)];
#pragma unroll
      for (int i = 0; i < 6; ++i)
        acc[i][jj] = __builtin_amdgcn_mfma_f32_16x16x32_bf16(af[i], bfr, acc[i][jj], 0, 0, 0);
    }
  }

#pragma unroll
  for (int jj = 0; jj < 2; ++jj) {
    int colL = wave * 32 + jj * 16;
    int d = (colL & 63) + m16;
    size_t obase = (size_t)(b * 96) * 64 * CC + (size_t)p_[jj] * CC + (bh & 15) * 64 + d;
#pragma unroll
    for (int i = 0; i < 6; ++i) {
#pragma unroll
      for (int r = 0; r < 4; ++r) {
        int n = i * 16 + quad * 4 + r;
        out2[obase + (size_t)n * (64 * CC)] = f2bf(acc[i][jj][r]);
      }
    }
  }
}

// ---------------------------------------------------------------------------
// Buffer plan identical to previous rounds (see chunked-ordering proof).
// ---------------------------------------------------------------------------
extern "C" void kernel_launch(void* const* d_in, const int* in_sizes, int n_in,
                              void* d_out, int out_size, void* d_ws, size_t ws_size,
                              hipStream_t stream) {
  const float* x      = (const float*)d_in[0];  // (4,96,64,1024) fp32
  const float* W_qkv  = (const float*)d_in[1];  // (1024,3072) fp32
  const float* W_proj = (const float*)d_in[2];  // (1024,1024) fp32
  const float* b_proj = (const float*)d_in[3];  // (1024,) fp32
  float* out = (float*)d_out;                   // (4,96,64,1024) fp32

  char* w = (char*)d_ws;
  unsigned short* WqkvT = (unsigned short*)(w);                    // 6 MB
  unsigned short* WpT   = (unsigned short*)(w + 6291456);          // 2 MB
  unsigned short* xm    = (unsigned short*)(w + 8388608);          // 0.75 MB
  float*          qkbuf = (float*)(w + 9175040);                   // 3 MB
  unsigned short* attn  = (unsigned short*)(w + 12320768);         // 1.125 MB
  unsigned short* out2w = (unsigned short*)(w + 13500416);         // 48 or 12 MB
  unsigned short* xbf   = (unsigned short*)d_out;                      // 48 MB
  unsigned short* Vbuf  = (unsigned short*)((char*)d_out + 50331648);  // 48 MB

  const bool fullws = ws_size >= (size_t)13500416 + 50331648;

  // 1) fused convert(x->bf16) + mean-pool over P (q/k only need the mean)
  conv_mean<<<dim3(384), 256, 0, stream>>>(x, xbf, xm);

  // 2) weight convert+transpose (B^T bf16 layout)
  transpose_f32_bf16<<<dim3(96, 32), 256, 0, stream>>>(W_qkv, WqkvT, 1024, 3072, 3072);
  transpose_f32_bf16<<<dim3(32, 32), 256, 0, stream>>>(W_proj, WpT, 1024, 1024, 1024);

  // 3) qk = xm @ W_qkv[:, :2048] -> fp32 (small; plain mapping)
  gemm_bt<true, false><<<dim3(48), 256, 0, stream>>>(
      xm, WqkvT, qkbuf, nullptr, 384, 2048, 1024, 16);

  // 4) scores + softmax -> attn bf16
  softmax_k<<<dim3(64), 128, 0, stream>>>(qkbuf, attn);

  // 5) V = xbf @ W_qkv[:, 2048:3072] -> bf16 (256x256 pipelined GEMM)
  gemm_bt256<false><<<dim3(384), 512, 0, stream>>>(
      xbf, WqkvT + (size_t)2048 * 1024, Vbuf, nullptr, 24576, 1024, 1024);

  if (fullws) {
    // 6) attn-mix, all batches in one launch (64 bh x 32 col-tiles)
    attn_apply_mfma<<<dim3(2048), 256, 0, stream>>>(attn, Vbuf, out2w);
    // 7) out = out2 @ W_proj + b_proj -> fp32, one full-M launch
    gemm_bt256<true><<<dim3(384), 512, 0, stream>>>(
        out2w, WpT, out, b_proj, 24576, 1024, 1024);
  } else {
    for (int b = 0; b < 4; ++b) {
      attn_apply_mfma<<<dim3(512), 256, 0, stream>>>(
          attn + (size_t)b * 16 * 96 * 96,
          Vbuf + (size_t)b * 6144 * 1024,
          out2w);
      gemm_bt256<true><<<dim3(96), 512, 0, stream>>>(
          out2w, WpT, out + (size_t)b * 6144 * 1024, b_proj, 6144, 1024, 1024);
    }
  }
}